// Round 9
// baseline (134.443 us; speedup 1.0000x reference)
//
#include <hip/hip_runtime.h>
#include <math.h>

#define N_BINS 229
#define MODEL  128
#define OUTD   88
#define WSZ    30
#define WLEN   61
#define BB     4
#define TT     2048
#define CTANH  2.8853900817779268f   // 2*log2(e)

#define ROWS_SC 16                   // rows per k_score / k_pool block
#define HALO    78                   // staged E rows: idx = (t-t0)+w in [0,77]
#define EPAD    33                   // float4 row stride (528B -> 4-bank rotate)
#define PHALO   76                   // pooling halo rows: s in [t0-30, t0+45]

__device__ __forceinline__ float sigmoidf_(float x) {
    return __builtin_amdgcn_rcpf(1.0f + __expf(-x));
}

// Bijective XCD swizzle (nwg % 8 == 0).
__device__ __forceinline__ int xcd_swz(int x, int nwg) {
    return (x & 7) * (nwg >> 3) + (x >> 3);
}

// ---------------- Pass 1: H = spec@W_h + b_attn ; E = spec@W_e ----------------
#define ROWS_HE 8
__global__ __launch_bounds__(256, 8) void k_he(
        const float* __restrict__ spec,
        const float* __restrict__ W_h,
        const float* __restrict__ W_e,
        const float* __restrict__ b_attn,
        float* __restrict__ H,
        float* __restrict__ E) {
    const int nb  = xcd_swz(blockIdx.x, gridDim.x);
    const int tid = threadIdx.x;
    __shared__ float s[ROWS_HE * N_BINS];              // 7328 B
    const float4* __restrict__ src4 =
        (const float4*)(spec + (size_t)nb * (ROWS_HE * N_BINS));
    float4* s4 = (float4*)s;
#pragma unroll
    for (int i = 0; i < 2; ++i) {
        int idx = i * 256 + tid;
        if (idx < (ROWS_HE * N_BINS) / 4) s4[idx] = src4[idx];
    }
    __syncthreads();

    const int  m   = tid & 127;
    const bool isH = tid < 128;
    const float* __restrict__ Wp = (isH ? W_h : W_e) + m;
    const float bias = isH ? b_attn[m] : 0.0f;

    float acc[ROWS_HE];
#pragma unroll
    for (int r = 0; r < ROWS_HE; ++r) acc[r] = 0.0f;

    float cur[8];
#pragma unroll
    for (int j = 0; j < 8; ++j) cur[j] = Wp[j * MODEL];

    for (int batch = 0; batch < 28; ++batch) {         // 28*8 = 224
        const int fb = batch * 8;
        float nxt[8];
        if (batch < 27) {
#pragma unroll
            for (int j = 0; j < 8; ++j) nxt[j] = Wp[(fb + 8 + j) * MODEL];
        }
#pragma unroll
        for (int j = 0; j < 8; ++j) {
            const float wv = cur[j];
#pragma unroll
            for (int r = 0; r < ROWS_HE; ++r)
                acc[r] = fmaf(s[r * N_BINS + fb + j], wv, acc[r]);
        }
        if (batch < 27) {
#pragma unroll
            for (int j = 0; j < 8; ++j) cur[j] = nxt[j];
        }
    }
    for (int f = 224; f < N_BINS; ++f) {
        const float wv = Wp[f * MODEL];
#pragma unroll
        for (int r = 0; r < ROWS_HE; ++r)
            acc[r] = fmaf(s[r * N_BINS + f], wv, acc[r]);
    }

    float* __restrict__ dst =
        (isH ? H : E) + (size_t)nb * ROWS_HE * MODEL + m;
#pragma unroll
    for (int r = 0; r < ROWS_HE; ++r) dst[r * MODEL] = acc[r] + bias;
}

// ---------------- Pass 2a: scores + softmax (LDS E halo) ----------------
// 512 threads = 8 waves = 8 row-pairs = 16 rows. E halo staged once in LDS
// (zero-filled outside [0,TT) == reference zero-pad). aEff written per-row
// into the first 64 floats of this block's own H rows (overlay-safe).
__global__ __launch_bounds__(512, 4) void k_score(
        const float* __restrict__ H,
        const float* __restrict__ E,
        const float* __restrict__ v_w,
        float* __restrict__ aeff,           // == H base (overlay)
        float* __restrict__ a_out) {
    const int nb   = xcd_swz(blockIdx.x, gridDim.x);
    const int tid  = threadIdx.x;
    const int wv   = tid >> 6;              // 0..7
    const int lane = tid & 63;
    const int r0   = nb * ROWS_SC;
    const int b    = r0 >> 11;              // T = 2048
    const int t0   = r0 & (TT - 1);
    const int rT   = r0 + wv * 2;
    const int t    = t0 + wv * 2;

    __shared__ float4 Es4[HALO * EPAD];     // 41184 B, pad-33 stride
    __shared__ float4 Hs4[ROWS_SC * 32];    //  8192 B
    __shared__ float4 Vs4[32];              //   512 B
    __shared__ float  scA[8][2][64];        //  4096 B  (total ~54 KB)

    // ---- stage E halo rows [t0-30, t0+47], zero-filled outside [0,TT) ----
    const float4* __restrict__ Eb4 = (const float4*)E + (size_t)b * TT * 32;
    for (int i = tid; i < HALO * 32; i += 512) {
        const int row = i >> 5, c4 = i & 31;
        const int s   = t0 - WSZ + row;
        float4 v = make_float4(0.f, 0.f, 0.f, 0.f);
        if (s >= 0 && s < TT) v = Eb4[(size_t)s * 32 + c4];
        Es4[row * EPAD + c4] = v;
    }
    Hs4[tid] = ((const float4*)H)[(size_t)r0 * 32 + tid];   // exactly 512
    if (tid < 32) Vs4[tid] = ((const float4*)v_w)[tid];
    __syncthreads();

    // ---- scores for pair (t, t+1): quad lane g owns chunks cq=4q+g ----
    const int g  = lane & 3;
    const int w0 = lane >> 2;
    int ro[4];
#pragma unroll
    for (int it = 0; it < 4; ++it)
        ro[it] = (wv * 2 + w0 + it * 16) * EPAD;    // idx in [0,77]

    const float4* __restrict__ HsT = &Hs4[(wv * 2) * 32];
    const float4* __restrict__ HsU = &Hs4[(wv * 2 + 1) * 32];

    float ppT[4] = {0.f, 0.f, 0.f, 0.f};
    float ppU[4] = {0.f, 0.f, 0.f, 0.f};
    float vs = 0.f;
#pragma unroll
    for (int q = 0; q < 8; ++q) {
        const int    cq = (q << 2) + g;
        const float4 hT = HsT[cq];
        const float4 hU = HsU[cq];
        const float4 vq = Vs4[cq];
        vs += (vq.x + vq.y) + (vq.z + vq.w);
        const float nx = -2.f * vq.x, ny = -2.f * vq.y,
                    nz = -2.f * vq.z, nw = -2.f * vq.w;
        const float aTx = hT.x * CTANH, aTy = hT.y * CTANH,
                    aTz = hT.z * CTANH, aTw = hT.w * CTANH;
        const float aUx = hU.x * CTANH, aUy = hU.y * CTANH,
                    aUz = hU.z * CTANH, aUw = hU.w * CTANH;
#pragma unroll
        for (int it = 0; it < 4; ++it) {
            const float4 ev = Es4[ro[it] + cq];
            const float ex = ev.x * CTANH, ey = ev.y * CTANH,
                        ez = ev.z * CTANH, ew = ev.w * CTANH;
            float u;
            u = __builtin_amdgcn_rcpf(__builtin_amdgcn_exp2f(ex + aTx) + 1.f);
            ppT[it] = fmaf(nx, u, ppT[it]);
            u = __builtin_amdgcn_rcpf(__builtin_amdgcn_exp2f(ex + aUx) + 1.f);
            ppU[it] = fmaf(nx, u, ppU[it]);
            u = __builtin_amdgcn_rcpf(__builtin_amdgcn_exp2f(ey + aTy) + 1.f);
            ppT[it] = fmaf(ny, u, ppT[it]);
            u = __builtin_amdgcn_rcpf(__builtin_amdgcn_exp2f(ey + aUy) + 1.f);
            ppU[it] = fmaf(ny, u, ppU[it]);
            u = __builtin_amdgcn_rcpf(__builtin_amdgcn_exp2f(ez + aTz) + 1.f);
            ppT[it] = fmaf(nz, u, ppT[it]);
            u = __builtin_amdgcn_rcpf(__builtin_amdgcn_exp2f(ez + aUz) + 1.f);
            ppU[it] = fmaf(nz, u, ppU[it]);
            u = __builtin_amdgcn_rcpf(__builtin_amdgcn_exp2f(ew + aTw) + 1.f);
            ppT[it] = fmaf(nw, u, ppT[it]);
            u = __builtin_amdgcn_rcpf(__builtin_amdgcn_exp2f(ew + aUw) + 1.f);
            ppU[it] = fmaf(nw, u, ppU[it]);
        }
    }

    vs += __shfl_xor(vs, 1, 64);
    vs += __shfl_xor(vs, 2, 64);
#pragma unroll
    for (int it = 0; it < 4; ++it) {
        float pT = ppT[it];
        pT += __shfl_xor(pT, 1, 64);
        pT += __shfl_xor(pT, 2, 64);
        float pU = ppU[it];
        pU += __shfl_xor(pU, 1, 64);
        pU += __shfl_xor(pU, 2, 64);
        const int w = w0 + it * 16;
        if (g == 0) {
            if (w < WLEN)            scA[wv][0][w]     = pT + vs;
            if (w >= 1 && w <= WLEN) scA[wv][1][w - 1] = pU + vs;
        }
    }

    // ---- softmax per row; aEff (masked) -> first 64 floats of H row ----
#pragma unroll
    for (int rr = 0; rr < 2; ++rr) {
        float x = (lane < WLEN) ? scA[wv][rr][lane] : -INFINITY;
        float mx = x;
#pragma unroll
        for (int d = 32; d >= 1; d >>= 1) mx = fmaxf(mx, __shfl_xor(mx, d, 64));
        float e = (lane < WLEN) ? __expf(x - mx) : 0.0f;
        float sm = e;
#pragma unroll
        for (int d = 32; d >= 1; d >>= 1) sm += __shfl_xor(sm, d, 64);
        const float a = e * __builtin_amdgcn_rcpf(sm);
        if (lane < WLEN) a_out[(size_t)(rT + rr) * WLEN + lane] = a;
        const int   sl   = (t + rr) + lane - WSZ;
        const float aval = (lane < WLEN && sl >= 0 && sl < TT) ? a : 0.0f;
        aeff[(size_t)(rT + rr) * MODEL + lane] = aval;   // all 64 lanes
    }
}

// ---------------- Pass 2b: transposed pooling + gemv + sigmoid ----------------
// 256 threads = 4 waves; block owns 16 rows. Each spec halo row is read ONCE
// and feeds 16 row-accumulators (lane = one f-column, wave = f-chunk).
__global__ __launch_bounds__(256, 8) void k_pool(
        const float* __restrict__ spec,
        const float* __restrict__ aeff,     // == H base (row r at r*128, 64 floats)
        const float* __restrict__ W1,
        const float* __restrict__ b1,
        float* __restrict__ pred) {
    const int nb   = xcd_swz(blockIdx.x, gridDim.x);
    const int tid  = threadIdx.x;
    const int wv   = tid >> 6;
    const int lane = tid & 63;
    const int r0   = nb * ROWS_SC;
    const int b    = r0 >> 11;
    const int t0   = r0 & (TT - 1);

    __shared__ float scA2[ROWS_SC][80];     //  5120 B: scA2[k][s_idx]=a_k[s_idx-k]
    __shared__ float wsum[ROWS_SC][232];    // 14848 B

    // fill shifted coefficients (zeros outside w in [0,63]; w=61..63 are 0)
    for (int i = tid; i < ROWS_SC * 80; i += 256) {
        const int k = i / 80, c = i - k * 80;
        const int w = c - k;
        float v = 0.0f;
        if (w >= 0 && w < 64) v = aeff[(size_t)(r0 + k) * MODEL + w];
        (&scA2[0][0])[i] = v;
    }
    __syncthreads();

    // ---- pooling: lane = one f-column; iterate halo rows once ----
    const int fstart = wv * 57 + (wv > 0 ? 1 : 0);      // 0,58,115,172
    const int cnt    = (wv == 0) ? 58 : 57;
    const bool valid = lane < cnt;
    const int  fcol  = fstart + (valid ? lane : 0);

    float acc[ROWS_SC];
#pragma unroll
    for (int k = 0; k < ROWS_SC; ++k) acc[k] = 0.0f;

    const float* __restrict__ sb = spec + (size_t)b * TT * N_BINS;
    for (int si = 0; si < PHALO; ++si) {
        const int s = t0 - WSZ + si;
        if (s < 0 || s >= TT) continue;                  // weights are 0 there
        const float c = valid ? sb[(size_t)s * N_BINS + fcol] : 0.0f;
#pragma unroll
        for (int k = 0; k < ROWS_SC; ++k)
            acc[k] = fmaf(scA2[k][si], c, acc[k]);       // LDS broadcast coeff
    }
    if (valid) {
#pragma unroll
        for (int k = 0; k < ROWS_SC; ++k) wsum[k][fcol] = acc[k];
    }
    __syncthreads();

    // ---- gemv + sigmoid: 176 threads, 8 rows each; 8-deep W1 prefetch ----
    if (tid < 176) {
        const int h = (tid >= 88) ? 1 : 0;
        const int o = tid - h * 88;
        const float* __restrict__ ws = &wsum[h * 8][0];
        float acc8[8];
        const float bv = b1[o];
#pragma unroll
        for (int j = 0; j < 8; ++j) acc8[j] = bv;
        const float* __restrict__ W1o = W1 + o;

        float cur[8];
#pragma unroll
        for (int j = 0; j < 8; ++j) cur[j] = W1o[j * OUTD];

        for (int batch = 0; batch < 28; ++batch) {       // 28*8 = 224
            const int fb = batch * 8;
            float nxt[8];
            if (batch < 27) {
#pragma unroll
                for (int j = 0; j < 8; ++j) nxt[j] = W1o[(fb + 8 + j) * OUTD];
            }
#pragma unroll
            for (int j = 0; j < 8; ++j) {
                const float w1v = cur[j];
                const int   f   = fb + j;
#pragma unroll
                for (int k = 0; k < 8; ++k)
                    acc8[k] = fmaf(ws[k * 232 + f], w1v, acc8[k]);
            }
            if (batch < 27) {
#pragma unroll
                for (int j = 0; j < 8; ++j) cur[j] = nxt[j];
            }
        }
        for (int f = 224; f < N_BINS; ++f) {
            const float w1v = W1o[f * OUTD];
#pragma unroll
            for (int k = 0; k < 8; ++k)
                acc8[k] = fmaf(ws[k * 232 + f], w1v, acc8[k]);
        }
        const size_t rb = (size_t)r0 + h * 8;
#pragma unroll
        for (int k = 0; k < 8; ++k)
            pred[(rb + k) * OUTD + o] = sigmoidf_(acc8[k]);
    }
}

extern "C" void kernel_launch(void* const* d_in, const int* in_sizes, int n_in,
                              void* d_out, int out_size, void* d_ws, size_t ws_size,
                              hipStream_t stream) {
    const float* spec   = (const float*)d_in[0];
    const float* W_h    = (const float*)d_in[1];
    const float* W_e    = (const float*)d_in[2];
    const float* b_attn = (const float*)d_in[3];
    const float* v_w    = (const float*)d_in[4];
    const float* W1     = (const float*)d_in[5];
    const float* b1     = (const float*)d_in[6];

    const int n_rows = BB * TT;                    // 8192
    float* H = (float*)d_ws;                       // 4 MB; aEff overlays row fronts
    float* E = H + (size_t)n_rows * MODEL;         // 4 MB

    float* pred  = (float*)d_out;                  // 8192*88
    float* a_out = pred + (size_t)n_rows * OUTD;   // 8192*61

    k_he   <<<n_rows / ROWS_HE, 256, 0, stream>>>(spec, W_h, W_e, b_attn, H, E);
    k_score<<<n_rows / ROWS_SC, 512, 0, stream>>>(H, E, v_w, H, a_out);
    k_pool <<<n_rows / ROWS_SC, 256, 0, stream>>>(spec, H, W1, b1, pred);
}

// Round 10
// 111.668 us; speedup vs baseline: 1.2040x; 1.2040x over previous
//
#include <hip/hip_runtime.h>
#include <math.h>

#define N_BINS 229
#define MODEL  128
#define OUTD   88
#define WSZ    30
#define WLEN   61
#define BB     4
#define TT     2048
#define CTANH  2.8853900817779268f   // 2*log2(e)

#define ROWS_HE 8
#define ROWS_SC 16
#define HALO    78                   // halo rows: hi = (t-t0)+w, t-t0<16, w<64
#define EPADU   68                   // u32 stride per E halo row (64 data + 4 pad)

__device__ __forceinline__ float sigmoidf_(float x) {
    return __builtin_amdgcn_rcpf(1.0f + __expf(-x));
}

// ---------------- Pass 1: H=(spec@W_h+b)*C ; Ebf=bf16(spec@W_e*C) ; S1=spec@W1 ----
// 384 threads: tid<128 -> H col, <256 -> E col, <344 -> S1 col (40 idle lanes).
__global__ __launch_bounds__(384, 4) void k_he(
        const float* __restrict__ spec,
        const float* __restrict__ W_h,
        const float* __restrict__ W_e,
        const float* __restrict__ W1,
        const float* __restrict__ b_attn,
        float* __restrict__ H,
        unsigned int* __restrict__ Ebf,
        float* __restrict__ S1) {
    const int nb  = blockIdx.x;
    const int tid = threadIdx.x;
    __shared__ float s[ROWS_HE * N_BINS];              // 7328 B
    const float4* __restrict__ src4 =
        (const float4*)(spec + (size_t)nb * (ROWS_HE * N_BINS));
    float4* s4 = (float4*)s;
    for (int i = tid; i < (ROWS_HE * N_BINS) / 4; i += 384) s4[i] = src4[i];
    __syncthreads();

    const float* __restrict__ Wp;
    int st, m;
    float bias = 0.0f;
    if (tid < 128)      { m = tid;        Wp = W_h + m; st = MODEL; bias = b_attn[m]; }
    else if (tid < 256) { m = tid - 128;  Wp = W_e + m; st = MODEL; }
    else                { m = tid - 256;  if (m > 87) m = 87; Wp = W1 + m; st = OUTD; }

    float acc[ROWS_HE];
#pragma unroll
    for (int r = 0; r < ROWS_HE; ++r) acc[r] = 0.0f;

    float cur[8];
#pragma unroll
    for (int j = 0; j < 8; ++j) cur[j] = Wp[j * st];

    for (int batch = 0; batch < 28; ++batch) {         // 28*8 = 224
        const int fb = batch * 8;
        float nxt[8];
        if (batch < 27) {
#pragma unroll
            for (int j = 0; j < 8; ++j) nxt[j] = Wp[(fb + 8 + j) * st];
        }
#pragma unroll
        for (int j = 0; j < 8; ++j) {
            const float wv = cur[j];
#pragma unroll
            for (int r = 0; r < ROWS_HE; ++r)
                acc[r] = fmaf(s[r * N_BINS + fb + j], wv, acc[r]);
        }
        if (batch < 27) {
#pragma unroll
            for (int j = 0; j < 8; ++j) cur[j] = nxt[j];
        }
    }
    for (int f = 224; f < N_BINS; ++f) {
        const float wv = Wp[f * st];
#pragma unroll
        for (int r = 0; r < ROWS_HE; ++r)
            acc[r] = fmaf(s[r * N_BINS + f], wv, acc[r]);
    }

    const int rg0 = nb * ROWS_HE;
    if (tid < 128) {
#pragma unroll
        for (int r = 0; r < ROWS_HE; ++r)
            H[(size_t)(rg0 + r) * MODEL + m] = (acc[r] + bias) * CTANH;
    } else if (tid < 256) {
#pragma unroll
        for (int r = 0; r < ROWS_HE; ++r) {
            const float val = acc[r] * CTANH;              // pre-scaled E
            const float pv  = __shfl_xor(val, 1, 64);      // partner element
            if ((m & 1) == 0) {                            // even m packs (m, m+1)
                const unsigned int lo = (__float_as_uint(val) + 0x8000u) >> 16;
                const unsigned int hi = (__float_as_uint(pv) + 0x8000u) & 0xFFFF0000u;
                Ebf[(size_t)(rg0 + r) * 64 + (m >> 1)] = hi | lo;
            }
        }
    } else if (tid < 344) {
#pragma unroll
        for (int r = 0; r < ROWS_HE; ++r)
            S1[(size_t)(rg0 + r) * OUTD + m] = acc[r];     // b1 added in k_pool
    }
}

// ---------------- Pass 2a: scores + softmax -> aeff (pair layout) ----------------
// 512 threads = 8 waves = 8 row-pairs = 16 rows. bf16 E halo staged in LDS once.
// aeff pair p at p*128: [0:64) aT (row t coefs by w), [64:128) aU shifted
// (aU[w] = a_{t+1}[w-1]) so both rows pool the same S1 halo row in k_pool.
__global__ __launch_bounds__(512, 6) void k_score(
        const float* __restrict__ H,
        const unsigned int* __restrict__ Ebf,
        const float* __restrict__ v_w,
        float* __restrict__ aeff,
        float* __restrict__ a_out) {
    const int nb   = blockIdx.x;
    const int tid  = threadIdx.x;
    const int wv   = tid >> 6;              // 0..7
    const int lane = tid & 63;
    const int r0   = nb * ROWS_SC;
    const int b    = r0 >> 11;              // T = 2048
    const int t0   = r0 & (TT - 1);
    const int rT   = r0 + wv * 2;
    const int t    = t0 + wv * 2;

    __shared__ unsigned int Ebs[HALO * EPADU];   // 21216 B
    __shared__ float4 Hs4[ROWS_SC * 32];         //  8192 B
    __shared__ float4 Vs4[32];                   //   512 B
    __shared__ float  scA[8][2][64];             //  4096 B  (total ~34 KB)

    // ---- stage bf16 E halo (zero outside [0,TT) == reference zero-pad) ----
    const uint4* __restrict__ Eb16 = (const uint4*)Ebf + (size_t)b * TT * 16;
    for (int i = tid; i < HALO * 16; i += 512) {
        const int row = i >> 4, c = i & 15;
        const int s   = t0 - WSZ + row;
        uint4 v = make_uint4(0u, 0u, 0u, 0u);
        if (s >= 0 && s < TT) v = Eb16[(size_t)s * 16 + c];
        *(uint4*)&Ebs[row * EPADU + (c << 2)] = v;
    }
    Hs4[tid] = ((const float4*)H)[(size_t)r0 * 32 + tid];   // exactly 512
    if (tid < 32) Vs4[tid] = ((const float4*)v_w)[tid];
    __syncthreads();

    const int g  = lane & 3;
    const int w0 = lane >> 2;
    int ro[4];
#pragma unroll
    for (int it = 0; it < 4; ++it)
        ro[it] = (wv * 2 + w0 + it * 16) * EPADU;           // hi in [0,77]

    const float4* __restrict__ HsT = &Hs4[(wv * 2) * 32];
    const float4* __restrict__ HsU = &Hs4[(wv * 2 + 1) * 32];

    float ppT[4] = {0.f, 0.f, 0.f, 0.f};
    float ppU[4] = {0.f, 0.f, 0.f, 0.f};
    float vs = 0.f;
#pragma unroll
    for (int q = 0; q < 8; ++q) {
        const int    cq = (q << 2) + g;
        const float4 hT = HsT[cq];          // pre-scaled by CTANH in k_he
        const float4 hU = HsU[cq];
        const float4 vq = Vs4[cq];
        vs += (vq.x + vq.y) + (vq.z + vq.w);
        const float nx = -2.f * vq.x, ny = -2.f * vq.y,
                    nz = -2.f * vq.z, nw = -2.f * vq.w;
#pragma unroll
        for (int it = 0; it < 4; ++it) {
            const uint2 e2 = *(const uint2*)&Ebs[ro[it] + (cq << 1)];
            const float f0 = __uint_as_float(e2.x << 16);
            const float f1 = __uint_as_float(e2.x & 0xFFFF0000u);
            const float f2 = __uint_as_float(e2.y << 16);
            const float f3 = __uint_as_float(e2.y & 0xFFFF0000u);
            float u;
            u = __builtin_amdgcn_rcpf(__builtin_amdgcn_exp2f(f0 + hT.x) + 1.f);
            ppT[it] = fmaf(nx, u, ppT[it]);
            u = __builtin_amdgcn_rcpf(__builtin_amdgcn_exp2f(f0 + hU.x) + 1.f);
            ppU[it] = fmaf(nx, u, ppU[it]);
            u = __builtin_amdgcn_rcpf(__builtin_amdgcn_exp2f(f1 + hT.y) + 1.f);
            ppT[it] = fmaf(ny, u, ppT[it]);
            u = __builtin_amdgcn_rcpf(__builtin_amdgcn_exp2f(f1 + hU.y) + 1.f);
            ppU[it] = fmaf(ny, u, ppU[it]);
            u = __builtin_amdgcn_rcpf(__builtin_amdgcn_exp2f(f2 + hT.z) + 1.f);
            ppT[it] = fmaf(nz, u, ppT[it]);
            u = __builtin_amdgcn_rcpf(__builtin_amdgcn_exp2f(f2 + hU.z) + 1.f);
            ppU[it] = fmaf(nz, u, ppU[it]);
            u = __builtin_amdgcn_rcpf(__builtin_amdgcn_exp2f(f3 + hT.w) + 1.f);
            ppT[it] = fmaf(nw, u, ppT[it]);
            u = __builtin_amdgcn_rcpf(__builtin_amdgcn_exp2f(f3 + hU.w) + 1.f);
            ppU[it] = fmaf(nw, u, ppU[it]);
        }
    }

    vs += __shfl_xor(vs, 1, 64);
    vs += __shfl_xor(vs, 2, 64);
#pragma unroll
    for (int it = 0; it < 4; ++it) {
        float pT = ppT[it];
        pT += __shfl_xor(pT, 1, 64);
        pT += __shfl_xor(pT, 2, 64);
        float pU = ppU[it];
        pU += __shfl_xor(pU, 1, 64);
        pU += __shfl_xor(pU, 2, 64);
        const int w = w0 + it * 16;
        if (g == 0) {
            if (w < WLEN)            scA[wv][0][w]     = pT + vs;
            if (w >= 1 && w <= WLEN) scA[wv][1][w - 1] = pU + vs;
        }
    }

    // ---- softmax per row; aeff pair layout (masked, row-U shifted) ----
    float* __restrict__ ap = aeff + (size_t)(nb * 8 + wv) * 128;
#pragma unroll
    for (int rr = 0; rr < 2; ++rr) {
        float x = (lane < WLEN) ? scA[wv][rr][lane] : -INFINITY;
        float mx = x;
#pragma unroll
        for (int d = 32; d >= 1; d >>= 1) mx = fmaxf(mx, __shfl_xor(mx, d, 64));
        float e = (lane < WLEN) ? __expf(x - mx) : 0.0f;
        float sm = e;
#pragma unroll
        for (int d = 32; d >= 1; d >>= 1) sm += __shfl_xor(sm, d, 64);
        const float a = e * __builtin_amdgcn_rcpf(sm);
        if (lane < WLEN) a_out[(size_t)(rT + rr) * WLEN + lane] = a;
        const int   sl   = (t + rr) + lane - WSZ;
        const float aval = (lane < WLEN && sl >= 0 && sl < TT) ? a : 0.0f;
        if (rr == 0) {
            ap[lane] = aval;                               // slots 61..63 = 0
        } else {
            const float sh = __shfl_up(aval, 1, 64);       // aU[w] = a_{t+1}[w-1]
            ap[64 + lane] = (lane >= 1 && lane <= WLEN) ? sh : 0.0f;
        }
    }
}

// ---------------- Pass 2b: 88-dim pooling over S1 + sigmoid ----------------
// pred[t] = sigmoid(sum_w aT[w] * S1[t+w-30] + b1). 512 threads = 8 waves =
// 8 pairs = 16 rows; S1 halo (78 x 88) staged once in LDS.
__global__ __launch_bounds__(512, 6) void k_pool(
        const float* __restrict__ S1,
        const float* __restrict__ aeff,
        const float* __restrict__ b1,
        float* __restrict__ pred) {
    const int nb   = blockIdx.x;
    const int tid  = threadIdx.x;
    const int wv   = tid >> 6;
    const int lane = tid & 63;
    const int r0   = nb * ROWS_SC;
    const int b    = r0 >> 11;
    const int t0   = r0 & (TT - 1);
    const int rT   = r0 + wv * 2;

    __shared__ float S1h[HALO][OUTD];       // 27456 B
    __shared__ float cf[8][128];            //  4096 B  (total ~31.5 KB)

    // ---- stage S1 halo (zero outside [0,TT)) ----
    const float4* __restrict__ Sb4 = (const float4*)S1 + (size_t)b * TT * 22;
    for (int i = tid; i < HALO * 22; i += 512) {
        const int row = i / 22, c = i - row * 22;
        const int s   = t0 - WSZ + row;
        float4 v = make_float4(0.f, 0.f, 0.f, 0.f);
        if (s >= 0 && s < TT) v = Sb4[(size_t)s * 22 + c];
        *(float4*)&S1h[row][c << 2] = v;
    }
    // ---- stage coefficients (8 pairs x 128) ----
    for (int i = tid; i < 8 * 128; i += 512)
        (&cf[0][0])[i] = aeff[(size_t)(nb * 8) * 128 + i];
    __syncthreads();

    // ---- pooling: lane = output col o (o=lane, and o=64+lane for lane<24) ----
    const int o2   = 64 + (lane < 24 ? lane : 23);
    float aT1 = 0.f, aT2 = 0.f, aU1 = 0.f, aU2 = 0.f;
    const int hb = wv * 2;
#pragma unroll 4
    for (int w = 0; w < 64; ++w) {
        const float at = cf[wv][w];                 // LDS broadcast
        const float au = cf[wv][64 + w];
        const float* __restrict__ row = &S1h[hb + w][0];
        const float c1 = row[lane];
        const float c2 = row[o2];
        aT1 = fmaf(at, c1, aT1);  aU1 = fmaf(au, c1, aU1);
        aT2 = fmaf(at, c2, aT2);  aU2 = fmaf(au, c2, aU2);
    }

    const float b1a = b1[lane];
    pred[(size_t)rT * OUTD + lane]       = sigmoidf_(aT1 + b1a);
    pred[(size_t)(rT + 1) * OUTD + lane] = sigmoidf_(aU1 + b1a);
    if (lane < 24) {
        const float b1b = b1[64 + lane];
        pred[(size_t)rT * OUTD + 64 + lane]       = sigmoidf_(aT2 + b1b);
        pred[(size_t)(rT + 1) * OUTD + 64 + lane] = sigmoidf_(aU2 + b1b);
    }
}

extern "C" void kernel_launch(void* const* d_in, const int* in_sizes, int n_in,
                              void* d_out, int out_size, void* d_ws, size_t ws_size,
                              hipStream_t stream) {
    const float* spec   = (const float*)d_in[0];
    const float* W_h    = (const float*)d_in[1];
    const float* W_e    = (const float*)d_in[2];
    const float* b_attn = (const float*)d_in[3];
    const float* v_w    = (const float*)d_in[4];
    const float* W1     = (const float*)d_in[5];
    const float* b1     = (const float*)d_in[6];

    const int n_rows = BB * TT;                       // 8192
    char* ws = (char*)d_ws;
    float*        H    = (float*)ws;                  // 4 MB   (CTANH-scaled)
    unsigned int* Ebf  = (unsigned int*)(ws + ((size_t)4 << 20));  // 2 MB bf16-packed
    float*        S1   = (float*)(ws + ((size_t)6 << 20));         // 2.875 MB
    float*        aeff = (float*)(ws + ((size_t)9 << 20));         // 2 MB

    float* pred  = (float*)d_out;                     // 8192*88
    float* a_out = pred + (size_t)n_rows * OUTD;      // 8192*61

    k_he   <<<n_rows / ROWS_HE, 384, 0, stream>>>(spec, W_h, W_e, W1, b_attn, H, Ebf, S1);
    k_score<<<n_rows / ROWS_SC, 512, 0, stream>>>(H, Ebf, v_w, aeff, a_out);
    k_pool <<<n_rows / ROWS_SC, 512, 0, stream>>>(S1, aeff, b1, pred);
}